// Round 8
// baseline (885.147 us; speedup 1.0000x reference)
//
#include <hip/hip_runtime.h>

typedef __attribute__((ext_vector_type(8))) short short8;
typedef __attribute__((ext_vector_type(4))) short short4_t;
typedef __attribute__((ext_vector_type(4))) float float4_t;
typedef __attribute__((ext_vector_type(16))) float float16_t;
typedef __attribute__((ext_vector_type(2))) int int2_t;

#define NTOK 4096
#define CDIM 256
#define BPB (NTOK * CDIM)
#define C1 0.0901684400555602f   /* log2(e) / sqrt(256) */

__device__ inline float bf2f(short s) {
    return __uint_as_float(((unsigned)(unsigned short)s) << 16);
}
__device__ inline short f2bf(float f) {
    unsigned u = __float_as_uint(f);
    return (short)((u + 0x7fffu + ((u >> 16) & 1u)) >> 16);
}
__device__ inline int cvtpk_bf16(float lo, float hi) {
    int d;
    asm("v_cvt_pk_bf16_f32 %0, %1, %2" : "=v"(d) : "v"(lo), "v"(hi));
    return d;
}
__device__ inline void gl_lds16(const void* g, void* l) {
    __builtin_amdgcn_global_load_lds(
        (const __attribute__((address_space(1))) unsigned int*)g,
        (__attribute__((address_space(3))) unsigned int*)l, 16, 0, 0);
}

// ---------------------------------------------------------------------------
// wprep2: sniff fused + W -> bf16 conversion (96 blocks).
// ---------------------------------------------------------------------------
__global__ __launch_bounds__(256) void wprep2(
    const void* __restrict__ Wq, const void* __restrict__ Wk,
    const void* __restrict__ Wv, const unsigned* __restrict__ x,
    int* __restrict__ flag, short* __restrict__ Wb)
{
    __shared__ int cs;
    if (threadIdx.x == 0) cs = 0;
    __syncthreads();
    int local = 0;
    for (int i = threadIdx.x; i < 1024; i += 256) {
        unsigned e = (x[i] >> 7) & 0xffu;
        if (e >= 100u && e <= 140u) local++;
    }
    atomicAdd(&cs, local);
    __syncthreads();
    const int isbf = (cs >= 512) ? 1 : 0;

    if (blockIdx.x == 0 && threadIdx.x == 0) flag[0] = isbf;

    const int base = (blockIdx.x * 256 + threadIdx.x) * 8;   // [0, 196608)
    const int wsel = base >> 16, off = base & 65535;
    const void* W = (wsel == 0) ? Wq : (wsel == 1) ? Wk : Wv;
    short8 v;
    if (isbf) {
        v = *(const short8*)((const short*)W + off);
    } else {
        const float* f = (const float*)W + off;
        float4 a = *(const float4*)f;
        float4 c4 = *(const float4*)(f + 4);
        v[0]=f2bf(a.x);  v[1]=f2bf(a.y);  v[2]=f2bf(a.z);  v[3]=f2bf(a.w);
        v[4]=f2bf(c4.x); v[5]=f2bf(c4.y); v[6]=f2bf(c4.z); v[7]=f2bf(c4.w);
    }
    *(short8*)(Wb + base) = v;
}

// ---------------------------------------------------------------------------
// qkv8 (R4-proven): one block = 64 tokens x ONE of {Q,K,V}.  Grid 768,
// 4 blocks/CU.  X A-frags direct from global; W register-double-buffered.
// Outputs: Q plain [n][d]; K 32-key swizzled tiles; V d-pair-row swizzled.
// ---------------------------------------------------------------------------
template <bool PIN>
__global__ __launch_bounds__(256, 4) void qkv8(
    const void* __restrict__ xv, const short* __restrict__ Wb,
    const void* __restrict__ bq, const void* __restrict__ bk,
    const void* __restrict__ bv,
    const int* __restrict__ flag, int b0,
    short* __restrict__ qbase, short* __restrict__ kbase,
    short* __restrict__ vtbase)
{
    int nt, bl, wsel;
    if (PIN) {
        const int bid = blockIdx.x;          // 768
        wsel = bid >> 8;                      // 0..2
        const int rem = bid & 255;
        bl = rem & 3; nt = rem >> 2;
    } else { nt = blockIdx.x; wsel = blockIdx.y; bl = blockIdx.z; }
    const int b = b0 + bl;
    const int n0 = nt * 64;
    const int tid = threadIdx.x;
    const int w = tid >> 6, lane = tid & 63, l15 = lane & 15, qd = lane >> 4;
    const int isbf = flag[0];

    __shared__ short obuf[64 * 264];          // output staging only

    // ---- A-frags straight from global, coalesced: lane l15 = token ----
    short8 af[8];
    {
        const int n = n0 + 16 * w + l15;
        if (isbf) {
            const short* xs = (const short*)xv + (size_t)b * (CDIM * NTOK) + n;
            #pragma unroll
            for (int s = 0; s < 8; ++s) {
                short8 v;
                #pragma unroll
                for (int e = 0; e < 8; ++e)
                    v[e] = xs[(s * 32 + qd * 8 + e) * NTOK];
                af[s] = v;
            }
        } else {
            const float* xf = (const float*)xv + (size_t)b * (CDIM * NTOK) + n;
            #pragma unroll
            for (int s = 0; s < 8; ++s) {
                short8 v;
                #pragma unroll
                for (int e = 0; e < 8; ++e)
                    v[e] = f2bf(xf[(s * 32 + qd * 8 + e) * NTOK]);
                af[s] = v;
            }
        }
    }

    const short* W = Wb + wsel * 65536;
    const void* bp = (wsel == 0) ? bq : (wsel == 1) ? bk : bv;

    // ---- MFMA: 16 d-groups x 8 k-steps, W reg-double-buffered ----
    short8 wv[8], wn[8];
    {
        const short* wr = W + l15 * 256 + qd * 8;
        #pragma unroll
        for (int s = 0; s < 8; ++s) wv[s] = *(const short8*)(wr + s * 32);
    }
    #pragma unroll 1
    for (int dg = 0; dg < 16; ++dg) {
        const int d = dg * 16 + l15;
        if (dg + 1 < 16) {
            const short* wr = W + (dg * 16 + 16 + l15) * 256 + qd * 8;
            #pragma unroll
            for (int s = 0; s < 8; ++s) wn[s] = *(const short8*)(wr + s * 32);
        }
        float4_t acc = {0.f, 0.f, 0.f, 0.f};
        #pragma unroll
        for (int s = 0; s < 8; ++s)
            acc = __builtin_amdgcn_mfma_f32_16x16x32_bf16(af[s], wv[s], acc, 0, 0, 0);
        const float bias = isbf ? bf2f(((const short*)bp)[d])
                                : ((const float*)bp)[d];
        if (wsel < 2) {
            #pragma unroll
            for (int r = 0; r < 4; ++r)
                obuf[(16 * w + 4 * qd + r) * 264 + d] = f2bf(acc[r] + bias);
        } else {
            #pragma unroll
            for (int r = 0; r < 4; ++r)
                obuf[d * 66 + (16 * w + 4 * qd + r)] = f2bf(acc[r] + bias);
        }
        #pragma unroll
        for (int s = 0; s < 8; ++s) wv[s] = wn[s];
    }
    __syncthreads();

    if (wsel == 0) {
        short* qdst = qbase + (size_t)bl * BPB;
        const int rl = tid >> 2;
        #pragma unroll
        for (int u = 0; u < 8; ++u) {
            const int cc = (tid & 3) + 4 * u;
            short8 vv = *(const short8*)&obuf[rl * 264 + cc * 8];
            *(short8*)(qdst + (size_t)(n0 + rl) * 256 + cc * 8) = vv;
        }
    } else if (wsel == 1) {
        short* kdst = kbase + (size_t)bl * BPB;
        const int rl = tid >> 2;
        const int tile = (n0 + rl) >> 5, rit = rl & 31;
        #pragma unroll
        for (int u = 0; u < 8; ++u) {
            const int ccp = (tid & 3) + 4 * u;          // stored position
            const int cc  = ccp ^ rit;                   // data chunk
            short8 vv = *(const short8*)&obuf[rl * 264 + cc * 8];
            *(short8*)(kdst + (size_t)tile * 8192 + rit * 256 + ccp * 8) = vv;
        }
    } else {
        short* vtdst = vtbase + (size_t)bl * BPB;
        const int d = tid;
        #pragma unroll
        for (int u = 0; u < 8; ++u) {
            short8 vv = *(const short8*)&obuf[d * 66 + u * 8];
            const int tile = (n0 >> 5) + (u >> 2), ck = u & 3;
            const int pos = ((d & 1) * 4 + ck) ^ ((d >> 1) & 7);
            *(short8*)(vtdst + (size_t)tile * 8192 + (d >> 1) * 64 + pos * 8) = vv;
        }
    }
}

// ---------------------------------------------------------------------------
// flash14: QBLK=256, 512 threads (8 dedup waves x 32 qrows, full d each),
// KVBLK=32, split8 (512 keys/block).  Per-wave instruction stream identical
// to flash13; 2 blocks/CU x 8 waves = 4 waves/SIMD (VGPR<=128 via bounds).
// ---------------------------------------------------------------------------
__global__ __launch_bounds__(512, 4) void flash14(
    const short* __restrict__ qb, const short* __restrict__ kb,
    const short* __restrict__ vtb,
    float* __restrict__ pO, float* __restrict__ pl)
{
    const int bid = blockIdx.x;               // 512: bl | half*4 | qt*32
    const int bl = bid & 3, half = (bid >> 2) & 7, qt = bid >> 5;
    const int q0 = qt * 256;
    const int tid = threadIdx.x;
    const int w = tid >> 6, lane = tid & 63, l31 = lane & 31, h = lane >> 5;

    __shared__ __align__(16) char smem[65536];
    short* kbufA = (short*)smem;               // 2 x 16 KB
    short* vbufA = (short*)(smem + 32768);     // 2 x 16 KB

    const short* Q  = qb  + (size_t)bl * BPB;
    const char*  Kc = (const char*)(kb  + (size_t)bl * BPB);
    const char*  Vc = (const char*)(vtb + (size_t)bl * BPB);

    short8 qf[16];
    {
        const short* qrow = Q + (size_t)(q0 + 32 * w + l31) * 256 + h * 8;
        #pragma unroll
        for (int s = 0; s < 16; ++s)
            qf[s] = *(const short8*)(qrow + s * 16);
    }

    float16_t oacc[8];
    #pragma unroll
    for (int dt = 0; dt < 8; ++dt)
        #pragma unroll
        for (int r = 0; r < 16; ++r) oacc[dt][r] = 0.f;
    float ll0 = 0.f, ll1 = 0.f, ll2 = 0.f, ll3 = 0.f;

    const int KT0 = half * 16, KT1 = KT0 + 16;

    // prologue: DMA tile KT0 -> buffer 0 (512 threads: 2 rounds of 8KB each)
    {
        const char* ks = Kc + ((size_t)KT0 << 14);
        const char* vs = Vc + ((size_t)KT0 << 14);
        char* kd = smem + tid * 16;
        char* vd = smem + 32768 + tid * 16;
        #pragma unroll
        for (int u = 0; u < 2; ++u) {
            gl_lds16(ks + u * 8192 + tid * 16, kd + u * 8192);
            gl_lds16(vs + u * 8192 + tid * 16, vd + u * 8192);
        }
    }

    float16_t se, so;
    #pragma unroll
    for (int r = 0; r < 16; ++r) { se[r] = 0.f; so[r] = 0.f; }
    short8 pa0, pa1;

    #pragma unroll 1
    for (int kt = KT0; kt < KT1; ++kt) {
        // ================= phase A =================
        if (kt > KT0) {
            #pragma unroll
            for (int r = 0; r < 16; ++r) se[r] = exp2f((se[r] + so[r]) * C1);
            #pragma unroll
            for (int g = 0; g < 4; ++g) {
                ll0 += se[4 * g + 0]; ll1 += se[4 * g + 1];
                ll2 += se[4 * g + 2]; ll3 += se[4 * g + 3];
            }
            {
                int x0 = cvtpk_bf16(se[0], se[1]);
                int y0 = cvtpk_bf16(se[4], se[5]);
                int z0 = cvtpk_bf16(se[2], se[3]);
                int u0 = cvtpk_bf16(se[6], se[7]);
                int2_t r1 = __builtin_amdgcn_permlane32_swap(x0, y0, false, false);
                int2_t r2 = __builtin_amdgcn_permlane32_swap(z0, u0, false, false);
                union { int i[4]; short8 s8; } uu;
                uu.i[0] = r1[0]; uu.i[1] = r2[0]; uu.i[2] = r1[1]; uu.i[3] = r2[1];
                pa0 = uu.s8;
                int x1 = cvtpk_bf16(se[8],  se[9]);
                int y1 = cvtpk_bf16(se[12], se[13]);
                int z1 = cvtpk_bf16(se[10], se[11]);
                int u1 = cvtpk_bf16(se[14], se[15]);
                int2_t r3 = __builtin_amdgcn_permlane32_swap(x1, y1, false, false);
                int2_t r4 = __builtin_amdgcn_permlane32_swap(z1, u1, false, false);
                union { int i[4]; short8 s8; } vv;
                vv.i[0] = r3[0]; vv.i[1] = r4[0]; vv.i[2] = r3[1]; vv.i[3] = r4[1];
                pa1 = vv.s8;
            }
            {
                const short* vprev = vbufA + ((kt + 1) & 1) * 8192;  // (kt-1)&1
                #pragma unroll
                for (int dt = 0; dt < 8; ++dt) {
                    const int d = 32 * dt + l31, d2 = d >> 1;
                    {
                        const int pos = (((d & 1) * 4 + h) ^ (d2 & 7));
                        short8 vf = *(const short8*)&vprev[d2 * 64 + pos * 8];
                        oacc[dt] = __builtin_amdgcn_mfma_f32_32x32x16_bf16(pa0, vf, oacc[dt], 0, 0, 0);
                    }
                    {
                        const int pos = (((d & 1) * 4 + 2 + h) ^ (d2 & 7));
                        short8 vf = *(const short8*)&vprev[d2 * 64 + pos * 8];
                        oacc[dt] = __builtin_amdgcn_mfma_f32_32x32x16_bf16(pa1, vf, oacc[dt], 0, 0, 0);
                    }
                }
            }
        }

        asm volatile("s_waitcnt vmcnt(0) lgkmcnt(0)" ::: "memory");
        __builtin_amdgcn_sched_barrier(0);
        __builtin_amdgcn_s_barrier();
        __builtin_amdgcn_sched_barrier(0);

        // ================= phase B =================
        if (kt + 1 < KT1) {
            const int alt = (kt + 1) & 1;
            const char* ks = Kc + ((size_t)(kt + 1) << 14);
            const char* vs = Vc + ((size_t)(kt + 1) << 14);
            char* kd = smem + alt * 16384 + tid * 16;
            char* vd = smem + 32768 + alt * 16384 + tid * 16;
            #pragma unroll
            for (int u = 0; u < 2; ++u) {
                gl_lds16(ks + u * 8192 + tid * 16, kd + u * 8192);
                gl_lds16(vs + u * 8192 + tid * 16, vd + u * 8192);
            }
        }

        {
            const short* kcur = kbufA + (kt & 1) * 8192;
            #pragma unroll
            for (int r = 0; r < 16; ++r) { se[r] = 0.f; so[r] = 0.f; }
            #pragma unroll
            for (int j = 0; j < 8; ++j) {
                short8 ka = *(const short8*)
                    &kcur[l31 * 256 + (((4 * j + h) ^ l31) * 8)];
                se = __builtin_amdgcn_mfma_f32_32x32x16_bf16(ka, qf[2 * j], se, 0, 0, 0);
                short8 kb2 = *(const short8*)
                    &kcur[l31 * 256 + (((4 * j + 2 + h) ^ l31) * 8)];
                so = __builtin_amdgcn_mfma_f32_32x32x16_bf16(kb2, qf[2 * j + 1], so, 0, 0, 0);
            }
        }
    }

    // ---- drain: exp/pack/PV for S(KT1-1); buffers at index 1 ----
    {
        #pragma unroll
        for (int r = 0; r < 16; ++r) se[r] = exp2f((se[r] + so[r]) * C1);
        #pragma unroll
        for (int g = 0; g < 4; ++g) {
            ll0 += se[4 * g + 0]; ll1 += se[4 * g + 1];
            ll2 += se[4 * g + 2]; ll3 += se[4 * g + 3];
        }
        int x0 = cvtpk_bf16(se[0], se[1]);
        int y0 = cvtpk_bf16(se[4], se[5]);
        int z0 = cvtpk_bf16(se[2], se[3]);
        int u0 = cvtpk_bf16(se[6], se[7]);
        int2_t r1 = __builtin_amdgcn_permlane32_swap(x0, y0, false, false);
        int2_t r2 = __builtin_amdgcn_permlane32_swap(z0, u0, false, false);
        union { int i[4]; short8 s8; } uu;
        uu.i[0] = r1[0]; uu.i[1] = r2[0]; uu.i[2] = r1[1]; uu.i[3] = r2[1];
        pa0 = uu.s8;
        int x1 = cvtpk_bf16(se[8],  se[9]);
        int y1 = cvtpk_bf16(se[12], se[13]);
        int z1 = cvtpk_bf16(se[10], se[11]);
        int u1 = cvtpk_bf16(se[14], se[15]);
        int2_t r3 = __builtin_amdgcn_permlane32_swap(x1, y1, false, false);
        int2_t r4 = __builtin_amdgcn_permlane32_swap(z1, u1, false, false);
        union { int i[4]; short8 s8; } vv;
        vv.i[0] = r3[0]; vv.i[1] = r4[0]; vv.i[2] = r3[1]; vv.i[3] = r4[1];
        pa1 = vv.s8;

        const short* vlast = vbufA + 8192;     // (KT1-1)&1 == 1 always
        #pragma unroll
        for (int dt = 0; dt < 8; ++dt) {
            const int d = 32 * dt + l31, d2 = d >> 1;
            {
                const int pos = (((d & 1) * 4 + h) ^ (d2 & 7));
                short8 vf = *(const short8*)&vlast[d2 * 64 + pos * 8];
                oacc[dt] = __builtin_amdgcn_mfma_f32_32x32x16_bf16(pa0, vf, oacc[dt], 0, 0, 0);
            }
            {
                const int pos = (((d & 1) * 4 + 2 + h) ^ (d2 & 7));
                short8 vf = *(const short8*)&vlast[d2 * 64 + pos * 8];
                oacc[dt] = __builtin_amdgcn_mfma_f32_32x32x16_bf16(pa1, vf, oacc[dt], 0, 0, 0);
            }
        }
    }

    // ---- epilogue: direct partial stores ----
    const int tile = bl * 16 + qt;            // 0..63
    const size_t idx = (size_t)tile * 8 + half;
    {
        float v2 = (ll0 + ll1) + (ll2 + ll3);
        v2 += __shfl_xor(v2, 32, 64);
        if (h == 0) pl[idx * 256 + 32 * w + l31] = v2;
    }
    float* po = pO + idx * 65536;
    #pragma unroll
    for (int dt = 0; dt < 8; ++dt) {
        #pragma unroll
        for (int r = 0; r < 16; ++r) {
            const int qrow = 32 * w + (r & 3) + 8 * (r >> 2) + 4 * h;
            po[qrow * 256 + 32 * dt + l31] = oacc[dt][r];
        }
    }
}

// ---------------------------------------------------------------------------
// combine8: coalesced.  One wave = one output row; 8 partials summed.
// Grid 512 x 256 threads; 32 rows per block.
// ---------------------------------------------------------------------------
__global__ __launch_bounds__(256) void combine8(
    const float* __restrict__ pO, const float* __restrict__ pl,
    const int* __restrict__ flag, void* __restrict__ outv)
{
    const int tid = threadIdx.x, w = tid >> 6, lane = tid & 63;
    const int isbf = flag[0];
    #pragma unroll 1
    for (int st = 0; st < 8; ++st) {
        const int row = blockIdx.x * 32 + st * 4 + w;     // [0, 16384)
        const int bl = row >> 12, n = row & 4095;
        const int qt = n >> 8, prow = n & 255;
        const size_t bidx = (size_t)(bl * 16 + qt) * 8;
        const float* P0 = pO + bidx * 65536 + prow * 256 + lane * 4;
        float4 r = *(const float4*)P0;
        float lsum = pl[bidx * 256 + prow];
        #pragma unroll
        for (int j = 1; j < 8; ++j) {
            float4 a = *(const float4*)(P0 + (size_t)j * 65536);
            r.x += a.x; r.y += a.y; r.z += a.z; r.w += a.w;
            lsum += pl[(bidx + j) * 256 + prow];
        }
        const float inv = 1.0f / lsum;
        r.x *= inv; r.y *= inv; r.z *= inv; r.w *= inv;
        const size_t o = (size_t)row * 256 + lane * 4;
        if (isbf) {
            short4_t pk;
            pk[0] = f2bf(r.x); pk[1] = f2bf(r.y);
            pk[2] = f2bf(r.z); pk[3] = f2bf(r.w);
            *(short4_t*)((short*)outv + o) = pk;
        } else {
            *(float4*)((float*)outv + o) = r;
        }
    }
}

// ---------------------------------------------------------------------------
// flash13 (R6-proven, 94 us): QBLK=128, 4 waves, split4.  Fallback tier.
// ---------------------------------------------------------------------------
__global__ __launch_bounds__(256, 2) void flash13(
    const short* __restrict__ qb, const short* __restrict__ kb,
    const short* __restrict__ vtb,
    float* __restrict__ pO, float* __restrict__ pl)
{
    const int bid = blockIdx.x;               // 512
    const int bl = bid & 3, half = (bid >> 2) & 3, qt = bid >> 4;
    const int q0 = qt * 128;
    const int tid = threadIdx.x;
    const int w = tid >> 6, lane = tid & 63, l31 = lane & 31, h = lane >> 5;

    __shared__ __align__(16) char smem[65536];
    short* kbufA = (short*)smem;
    short* vbufA = (short*)(smem + 32768);

    const short* Q  = qb  + (size_t)bl * BPB;
    const char*  Kc = (const char*)(kb  + (size_t)bl * BPB);
    const char*  Vc = (const char*)(vtb + (size_t)bl * BPB);

    short8 qf[16];
    {
        const short* qrow = Q + (size_t)(q0 + 32 * w + l31) * 256 + h * 8;
        #pragma unroll
        for (int s = 0; s < 16; ++s)
            qf[s] = *(const short8*)(qrow + s * 16);
    }

    float16_t oacc[8];
    #pragma unroll
    for (int dt = 0; dt < 8; ++dt)
        #pragma unroll
        for (int r = 0; r < 16; ++r) oacc[dt][r] = 0.f;
    float ll0 = 0.f, ll1 = 0.f, ll2 = 0.f, ll3 = 0.f;

    const int KT0 = half * 32, KT1 = KT0 + 32;

    {
        const char* ks = Kc + ((size_t)KT0 << 14);
        const char* vs = Vc + ((size_t)KT0 << 14);
        char* kd = smem + tid * 16;
        char* vd = smem + 32768 + tid * 16;
        #pragma unroll
        for (int u = 0; u < 4; ++u) {
            gl_lds16(ks + u * 4096 + tid * 16, kd + u * 4096);
            gl_lds16(vs + u * 4096 + tid * 16, vd + u * 4096);
        }
    }

    float16_t se, so;
    #pragma unroll
    for (int r = 0; r < 16; ++r) { se[r] = 0.f; so[r] = 0.f; }
    short8 pa0, pa1;

    #pragma unroll 1
    for (int kt = KT0; kt < KT1; ++kt) {
        if (kt > KT0) {
            #pragma unroll
            for (int r = 0; r < 16; ++r) se[r] = exp2f((se[r] + so[r]) * C1);
            #pragma unroll
            for (int g = 0; g < 4; ++g) {
                ll0 += se[4 * g + 0]; ll1 += se[4 * g + 1];
                ll2 += se[4 * g + 2]; ll3 += se[4 * g + 3];
            }
            {
                int x0 = cvtpk_bf16(se[0], se[1]);
                int y0 = cvtpk_bf16(se[4], se[5]);
                int z0 = cvtpk_bf16(se[2], se[3]);
                int u0 = cvtpk_bf16(se[6], se[7]);
                int2_t r1 = __builtin_amdgcn_permlane32_swap(x0, y0, false, false);
                int2_t r2 = __builtin_amdgcn_permlane32_swap(z0, u0, false, false);
                union { int i[4]; short8 s8; } uu;
                uu.i[0] = r1[0]; uu.i[1] = r2[0]; uu.i[2] = r1[1]; uu.i[3] = r2[1];
                pa0 = uu.s8;
                int x1 = cvtpk_bf16(se[8],  se[9]);
                int y1 = cvtpk_bf16(se[12], se[13]);
                int z1 = cvtpk_bf16(se[10], se[11]);
                int u1 = cvtpk_bf16(se[14], se[15]);
                int2_t r3 = __builtin_amdgcn_permlane32_swap(x1, y1, false, false);
                int2_t r4 = __builtin_amdgcn_permlane32_swap(z1, u1, false, false);
                union { int i[4]; short8 s8; } vv;
                vv.i[0] = r3[0]; vv.i[1] = r4[0]; vv.i[2] = r3[1]; vv.i[3] = r4[1];
                pa1 = vv.s8;
            }
            {
                const short* vprev = vbufA + ((kt + 1) & 1) * 8192;
                #pragma unroll
                for (int dt = 0; dt < 8; ++dt) {
                    const int d = 32 * dt + l31, d2 = d >> 1;
                    {
                        const int pos = (((d & 1) * 4 + h) ^ (d2 & 7));
                        short8 vf = *(const short8*)&vprev[d2 * 64 + pos * 8];
                        oacc[dt] = __builtin_amdgcn_mfma_f32_32x32x16_bf16(pa0, vf, oacc[dt], 0, 0, 0);
                    }
                    {
                        const int pos = (((d & 1) * 4 + 2 + h) ^ (d2 & 7));
                        short8 vf = *(const short8*)&vprev[d2 * 64 + pos * 8];
                        oacc[dt] = __builtin_amdgcn_mfma_f32_32x32x16_bf16(pa1, vf, oacc[dt], 0, 0, 0);
                    }
                }
            }
        }

        asm volatile("s_waitcnt vmcnt(0) lgkmcnt(0)" ::: "memory");
        __builtin_amdgcn_sched_barrier(0);
        __builtin_amdgcn_s_barrier();
        __builtin_amdgcn_sched_barrier(0);

        if (kt + 1 < KT1) {
            const int alt = (kt + 1) & 1;
            const char* ks = Kc + ((size_t)(kt + 1) << 14);
            const char* vs = Vc + ((size_t)(kt + 1) << 14);
            char* kd = smem + alt * 16384 + tid * 16;
            char* vd = smem + 32768 + alt * 16384 + tid * 16;
            #pragma unroll
            for (int u = 0; u < 4; ++u) {
                gl_lds16(ks + u * 4096 + tid * 16, kd + u * 4096);
                gl_lds16(vs + u * 4096 + tid * 16, vd + u * 4096);
            }
        }

        {
            const short* kcur = kbufA + (kt & 1) * 8192;
            #pragma unroll
            for (int r = 0; r < 16; ++r) { se[r] = 0.f; so[r] = 0.f; }
            #pragma unroll
            for (int j = 0; j < 8; ++j) {
                short8 ka = *(const short8*)
                    &kcur[l31 * 256 + (((4 * j + h) ^ l31) * 8)];
                se = __builtin_amdgcn_mfma_f32_32x32x16_bf16(ka, qf[2 * j], se, 0, 0, 0);
                short8 kb2 = *(const short8*)
                    &kcur[l31 * 256 + (((4 * j + 2 + h) ^ l31) * 8)];
                so = __builtin_amdgcn_mfma_f32_32x32x16_bf16(kb2, qf[2 * j + 1], so, 0, 0, 0);
            }
        }
    }

    {
        #pragma unroll
        for (int r = 0; r < 16; ++r) se[r] = exp2f((se[r] + so[r]) * C1);
        #pragma unroll
        for (int g = 0; g < 4; ++g) {
            ll0 += se[4 * g + 0]; ll1 += se[4 * g + 1];
            ll2 += se[4 * g + 2]; ll3 += se[4 * g + 3];
        }
        int x0 = cvtpk_bf16(se[0], se[1]);
        int y0 = cvtpk_bf16(se[4], se[5]);
        int z0 = cvtpk_bf16(se[2], se[3]);
        int u0 = cvtpk_bf16(se[6], se[7]);
        int2_t r1 = __builtin_amdgcn_permlane32_swap(x0, y0, false, false);
        int2_t r2 = __builtin_amdgcn_permlane32_swap(z0, u0, false, false);
        union { int i[4]; short8 s8; } uu;
        uu.i[0] = r1[0]; uu.i[1] = r2[0]; uu.i[2] = r1[1]; uu.i[3] = r2[1];
        pa0 = uu.s8;
        int x1 = cvtpk_bf16(se[8],  se[9]);
        int y1 = cvtpk_bf16(se[12], se[13]);
        int z1 = cvtpk_bf16(se[10], se[11]);
        int u1 = cvtpk_bf16(se[14], se[15]);
        int2_t r3 = __builtin_amdgcn_permlane32_swap(x1, y1, false, false);
        int2_t r4 = __builtin_amdgcn_permlane32_swap(z1, u1, false, false);
        union { int i[4]; short8 s8; } vv;
        vv.i[0] = r3[0]; vv.i[1] = r4[0]; vv.i[2] = r3[1]; vv.i[3] = r4[1];
        pa1 = vv.s8;

        const short* vlast = vbufA + 8192;
        #pragma unroll
        for (int dt = 0; dt < 8; ++dt) {
            const int d = 32 * dt + l31, d2 = d >> 1;
            {
                const int pos = (((d & 1) * 4 + h) ^ (d2 & 7));
                short8 vf = *(const short8*)&vlast[d2 * 64 + pos * 8];
                oacc[dt] = __builtin_amdgcn_mfma_f32_32x32x16_bf16(pa0, vf, oacc[dt], 0, 0, 0);
            }
            {
                const int pos = (((d & 1) * 4 + 2 + h) ^ (d2 & 7));
                short8 vf = *(const short8*)&vlast[d2 * 64 + pos * 8];
                oacc[dt] = __builtin_amdgcn_mfma_f32_32x32x16_bf16(pa1, vf, oacc[dt], 0, 0, 0);
            }
        }
    }

    const size_t idx = (size_t)(bl * 32 + qt) * 4 + half;
    {
        float v2 = (ll0 + ll1) + (ll2 + ll3);
        v2 += __shfl_xor(v2, 32, 64);
        if (h == 0) pl[idx * 128 + 32 * w + l31] = v2;
    }
    float* po = pO + idx * 32768;
    #pragma unroll
    for (int dt = 0; dt < 8; ++dt) {
        #pragma unroll
        for (int r = 0; r < 16; ++r) {
            const int qrow = 32 * w + (r & 3) + 8 * (r >> 2) + 4 * h;
            po[qrow * 256 + 32 * dt + l31] = oacc[dt][r];
        }
    }
}

// ---------------------------------------------------------------------------
// combine4 (R5-proven, coalesced): one wave = one output row.
// ---------------------------------------------------------------------------
__global__ __launch_bounds__(256) void combine4(
    const float* __restrict__ pO, const float* __restrict__ pl,
    const int* __restrict__ flag, void* __restrict__ outv)
{
    const int tid = threadIdx.x, w = tid >> 6, lane = tid & 63;
    const int isbf = flag[0];
    #pragma unroll 1
    for (int st = 0; st < 16; ++st) {
        const int row = blockIdx.x * 64 + st * 4 + w;     // [0, 16384)
        const int bl = row >> 12, n = row & 4095;
        const int qt = n >> 7, prow = n & 127;
        const size_t bidx = (size_t)(bl * 32 + qt) * 4;
        const float* P0 = pO + bidx * 32768 + prow * 256 + lane * 4;
        float4 a = *(const float4*)P0;
        float4 b = *(const float4*)(P0 + 32768);
        float4 c = *(const float4*)(P0 + 65536);
        float4 d = *(const float4*)(P0 + 98304);
        const float inv = 1.0f /
            (pl[(bidx + 0) * 128 + prow] + pl[(bidx + 1) * 128 + prow] +
             pl[(bidx + 2) * 128 + prow] + pl[(bidx + 3) * 128 + prow]);
        float4 r;
        r.x = (a.x + b.x + c.x + d.x) * inv;
        r.y = (a.y + b.y + c.y + d.y) * inv;
        r.z = (a.z + b.z + c.z + d.z) * inv;
        r.w = (a.w + b.w + c.w + d.w) * inv;
        const size_t o = (size_t)row * 256 + lane * 4;
        if (isbf) {
            short4_t pk;
            pk[0] = f2bf(r.x); pk[1] = f2bf(r.y);
            pk[2] = f2bf(r.z); pk[3] = f2bf(r.w);
            *(short4_t*)((short*)outv + o) = pk;
        } else {
            *(float4*)((float*)outv + o) = r;
        }
    }
}

// ---------------------------------------------------------------------------
// flash12 (small-ws fallback): QBLK=64, KVBLK=32, no split, direct output.
// ---------------------------------------------------------------------------
template <bool PIN>
__global__ __launch_bounds__(256, 2) void flash12(
    int b0, const short* __restrict__ qb, const short* __restrict__ kb,
    const short* __restrict__ vtb, const int* __restrict__ flag,
    void* __restrict__ outv)
{
    int qt, bl;
    if (PIN) { bl = blockIdx.x & 3; qt = blockIdx.x >> 2; }
    else     { qt = blockIdx.x; bl = blockIdx.z; }

    const int b = b0 + bl;
    const int q0 = qt * 64;
    const int tid = threadIdx.x;
    const int w = tid >> 6, lane = tid & 63, l31 = lane & 31, h = lane >> 5;
    const int wi = w & 1, wh = w >> 1;

    __shared__ __align__(16) char smem[67584];
    short* kbufA = (short*)smem;
    short* vbufA = (short*)(smem + 32768);
    float* lbuf  = (float*)(smem + 66560);

    const short* Q  = qb  + (size_t)bl * BPB;
    const char*  Kc = (const char*)(kb  + (size_t)bl * BPB);
    const char*  Vc = (const char*)(vtb + (size_t)bl * BPB);

    short8 qf[16];
    {
        const short* qrow = Q + (size_t)(q0 + 32 * wh + l31) * 256 + h * 8;
        #pragma unroll
        for (int s = 0; s < 16; ++s)
            qf[s] = *(const short8*)(qrow + s * 16);
    }

    float16_t oacc[4];
    #pragma unroll
    for (int dt = 0; dt < 4; ++dt)
        #pragma unroll
        for (int r = 0; r < 16; ++r) oacc[dt][r] = 0.f;
    float ll0 = 0.f, ll1 = 0.f, ll2 = 0.f, ll3 = 0.f;

    {
        const char* ks = Kc;
        const char* vs = Vc;
        char* kd = smem + tid * 16;
        char* vd = smem + 32768 + tid * 16;
        #pragma unroll
        for (int u = 0; u < 4; ++u) {
            gl_lds16(ks + u * 4096 + tid * 16, kd + u * 4096);
            gl_lds16(vs + u * 4096 + tid * 16, vd + u * 4096);
        }
    }
    __syncthreads();

    short8 pa0 = {0,0,0,0,0,0,0,0}, pa1 = {0,0,0,0,0,0,0,0};

    #pragma unroll 1
    for (int kt = 0; kt < 128; ++kt) {
        short* kcur  = kbufA + (kt & 1) * 8192;
        short* vprev = vbufA + ((kt + 1) & 1) * 8192;

        if (kt + 1 < 128) {
            const char* ks = Kc + ((size_t)(kt + 1) << 14);
            char* kd = smem + (((kt + 1) & 1) << 14) + tid * 16;
            #pragma unroll
            for (int u = 0; u < 4; ++u)
                gl_lds16(ks + u * 4096 + tid * 16, kd + u * 4096);
        }

        float16_t se, so;
        #pragma unroll
        for (int r = 0; r < 16; ++r) { se[r] = 0.f; so[r] = 0.f; }
        #pragma unroll
        for (int j = 0; j < 8; ++j) {
            short8 ka = *(const short8*)
                &kcur[l31 * 256 + (((4 * j + h) ^ l31) * 8)];
            se = __builtin_amdgcn_mfma_f32_32x32x16_bf16(ka, qf[2 * j], se, 0, 0, 0);
            short8 kb2 = *(const short8*)
                &kcur[l31 * 256 + (((4 * j + 2 + h) ^ l31) * 8)];
            so = __builtin_amdgcn_mfma_f32_32x32x16_bf16(kb2, qf[2 * j + 1], so, 0, 0, 0);
        }

        if (kt > 0) {
            #pragma unroll
            for (int dt = 0; dt < 4; ++dt) {
                const int d = 128 * wi + 32 * dt + l31, d2 = d >> 1;
                {
                    const int pos = (((d & 1) * 4 + h) ^ (d2 & 7));
                    short8 vf = *(const short8*)&vprev[d2 * 64 + pos * 8];
                    oacc[dt] = __builtin_amdgcn_mfma_f32_32x32x16_bf16(pa0, vf, oacc[dt], 0, 0, 0);
                }
                {
                    const int pos = (((d & 1) * 4 + 2 + h) ^ (d2 & 7));
                    short8 vf = *(const short8*)&vprev[d2 * 64 + pos * 8];
                    oacc[dt] = __builtin_amdgcn_mfma_f32_32x32x16_bf16(pa1, vf, oacc[dt], 0, 0, 0);
                }
            }
        }

        asm volatile("s_waitcnt lgkmcnt(0)" ::: "memory");
        __builtin_amdgcn_sched_barrier(0);
        __builtin_amdgcn_s_barrier();
        __builtin_amdgcn_sched_barrier(0);

        if (kt + 1 < 128) {
            const char* vs = Vc + ((size_t)(kt + 1) << 14);
            char* vd = smem + 32768 + (((kt + 1) & 1) << 14) + tid * 16;
            #pragma unroll
            for (int u = 0; u < 4; ++u)
                gl_lds16(vs + u * 4096 + tid * 16, vd + u * 4096);
        }

        float pf[16];
        #pragma unroll
        for (int r = 0; r < 16; ++r) pf[r] = exp2f((se[r] + so[r]) * C1);
        #pragma unroll
        for (int g = 0; g < 4; ++g) {
            ll0 += pf[4 * g + 0]; ll1 += pf[4 * g + 1];
            ll2 += pf[4 * g + 2]; ll3 += pf[4 * g + 3];
        }
        {
            int x0 = cvtpk_bf16(pf[0], pf[1]);
            int y0 = cvtpk_bf16(pf[4], pf[5]);
            int z0 = cvtpk_bf16(pf[2], pf[3]);
            int u0 = cvtpk_bf16(pf[6], pf[7]);
            int2_t r1 = __builtin_amdgcn_permlane32_swap(x0, y0, false, false);
            int2_t r2 = __builtin_amdgcn_permlane32_swap(z0, u0, false, false);
            union { int i[4]; short8 s8; } uu;
            uu.i[0] = r1[0]; uu.i[1] = r2[0]; uu.i[2] = r1[1]; uu.i[3] = r2[1];
            pa0 = uu.s8;
            int x1 = cvtpk_bf16(pf[8],  pf[9]);
            int y1 = cvtpk_bf16(pf[12], pf[13]);
            int z1 = cvtpk_bf16(pf[10], pf[11]);
            int u1 = cvtpk_bf16(pf[14], pf[15]);
            int2_t r3 = __builtin_amdgcn_permlane32_swap(x1, y1, false, false);
            int2_t r4 = __builtin_amdgcn_permlane32_swap(z1, u1, false, false);
            union { int i[4]; short8 s8; } vv;
            vv.i[0] = r3[0]; vv.i[1] = r4[0]; vv.i[2] = r3[1]; vv.i[3] = r4[1];
            pa1 = vv.s8;
        }

        __syncthreads();
    }

    {
        short* vlast = vbufA + 8192;
        #pragma unroll
        for (int dt = 0; dt < 4; ++dt) {
            const int d = 128 * wi + 32 * dt + l31, d2 = d >> 1;
            {
                const int pos = (((d & 1) * 4 + h) ^ (d2 & 7));
                short8 vf = *(const short8*)&vlast[d2 * 64 + pos * 8];
                oacc[dt] = __builtin_amdgcn_mfma_f32_32x32x16_bf16(pa0, vf, oacc[dt], 0, 0, 0);
            }
            {
                const int pos = (((d & 1) * 4 + 2 + h) ^ (d2 & 7));
                short8 vf = *(const short8*)&vlast[d2 * 64 + pos * 8];
                oacc[dt] = __builtin_amdgcn_mfma_f32_32x32x16_bf16(pa1, vf, oacc[dt], 0, 0, 0);
            }
        }
    }

    {
        float v2 = (ll0 + ll1) + (ll2 + ll3);
        v2 += __shfl_xor(v2, 32, 64);
        if (h == 0 && wi == 0) lbuf[32 * wh + l31] = v2;
    }

    __syncthreads();
    float* obuf = (float*)smem;
    #pragma unroll
    for (int dt = 0; dt < 4; ++dt) {
        const int dim = 128 * wi + 32 * dt + l31;
        #pragma unroll
        for (int r = 0; r < 16; ++r) {
            const int qrow = 32 * wh + (r & 3) + 8 * (r >> 2) + 4 * h;
            obuf[qrow * 260 + dim] = oacc[dt][r];
        }
    }
    __syncthreads();
    {
        const int row = tid >> 2, q4 = (tid & 3) * 64;
        const float inv = 1.0f / lbuf[row];
        const float* src = obuf + row * 260 + q4;
        const size_t o = (size_t)(b * NTOK + q0 + row) * 256 + q4;
        if (flag[0]) {
            short* op = (short*)outv;
            #pragma unroll
            for (int g = 0; g < 4; ++g) {
                float4 a  = *(const float4*)(src + g * 8);
                float4 c4 = *(const float4*)(src + g * 8 + 4);
                short8 pk;
                pk[0]=f2bf(a.x*inv);  pk[1]=f2bf(a.y*inv);
                pk[2]=f2bf(a.z*inv);  pk[3]=f2bf(a.w*inv);
                pk[4]=f2bf(c4.x*inv); pk[5]=f2bf(c4.y*inv);
                pk[6]=f2bf(c4.z*inv); pk[7]=f2bf(c4.w*inv);
                *(short8*)(op + o + g * 8) = pk;
            }
        } else {
            float* op = (float*)outv;
            #pragma unroll
            for (int g = 0; g < 16; ++g) {
                float4 a = *(const float4*)(src + g * 4);
                a.x *= inv; a.y *= inv; a.z *= inv; a.w *= inv;
                *(float4*)(op + o + g * 4) = a;
            }
        }
    }
}

extern "C" void kernel_launch(void* const* d_in, const int* in_sizes, int n_in,
                              void* d_out, int out_size, void* d_ws, size_t ws_size,
                              hipStream_t stream)
{
    const size_t HDR = 1024;
    const size_t WBB = 393216;                     // 3 x 256 x 256 bf16
    const size_t TB  = (size_t)BPB * 2;            // 2 MB per batch per tensor
    const size_t OFF_K = HDR + WBB;
    const size_t need_prim = OFF_K + 12 * TB;                  // ~24.6 MB
    const size_t PO4 = 67108864;                                // split4 partials
    const size_t need_s4 = need_prim + PO4 + 262144;            // ~92 MB
    const size_t PO8 = 134217728;                               // split8 partials
    const size_t need_s8 = need_prim + PO8 + 1048576;           // ~160 MB

    int*   flag = (int*)d_ws;
    short* Wb   = (short*)((char*)d_ws + HDR);

    wprep2<<<96, 256, 0, stream>>>(
        d_in[1], d_in[3], d_in[5], (const unsigned*)d_in[0], flag, Wb);

    if (ws_size >= need_prim) {
        short* kbase  = (short*)((char*)d_ws + OFF_K);
        short* vtbase = kbase  + 4 * (size_t)BPB;
        short* qbase  = vtbase + 4 * (size_t)BPB;
        qkv8<true><<<dim3(768, 1, 1), 256, 0, stream>>>(
            d_in[0], Wb, d_in[2], d_in[4], d_in[6], flag, 0,
            qbase, kbase, vtbase);
        if (ws_size >= need_s8) {
            float* pO = (float*)((char*)d_ws + need_prim);
            float* pl = (float*)((char*)d_ws + need_prim + PO8);
            flash14<<<dim3(512, 1, 1), 512, 0, stream>>>(
                qbase, kbase, vtbase, pO, pl);
            combine8<<<dim3(512, 1, 1), 256, 0, stream>>>(pO, pl, flag, d_out);
        } else if (ws_size >= need_s4) {
            float* pO = (float*)((char*)d_ws + need_prim);
            float* pl = (float*)((char*)d_ws + need_prim + PO4);
            flash13<<<dim3(512, 1, 1), 256, 0, stream>>>(
                qbase, kbase, vtbase, pO, pl);
            combine4<<<dim3(256, 1, 1), 256, 0, stream>>>(pO, pl, flag, d_out);
        } else {
            flash12<true><<<dim3(256, 1, 1), 256, 0, stream>>>(
                0, qbase, kbase, vtbase, flag, d_out);
        }
        return;
    }

    // fallback: batch-chunked
    int nb = 4;
    while (nb > 1 && ws_size < OFF_K + (size_t)nb * 3 * TB) nb--;
    short* kbase  = (short*)((char*)d_ws + OFF_K);
    short* vtbase = kbase + (size_t)nb * BPB;
    short* qbase  = vtbase + (size_t)nb * BPB;

    for (int b0 = 0; b0 < 4; b0 += nb) {
        const int nbc = (4 - b0) < nb ? (4 - b0) : nb;
        qkv8<false><<<dim3(64, 3, nbc), 256, 0, stream>>>(
            d_in[0], Wb, d_in[2], d_in[4], d_in[6], flag, b0,
            qbase, kbase, vtbase);
        flash12<false><<<dim3(64, 1, nbc), 256, 0, stream>>>(
            b0, qbase, kbase, vtbase, flag, d_out);
    }
}

// Round 9
// 222.984 us; speedup vs baseline: 3.9696x; 3.9696x over previous
//
#include <hip/hip_runtime.h>

typedef __attribute__((ext_vector_type(8))) short short8;
typedef __attribute__((ext_vector_type(4))) short short4_t;
typedef __attribute__((ext_vector_type(4))) float float4_t;
typedef __attribute__((ext_vector_type(16))) float float16_t;
typedef __attribute__((ext_vector_type(2))) int int2_t;

#define NTOK 4096
#define CDIM 256
#define BPB (NTOK * CDIM)
#define C1 0.0901684400555602f   /* log2(e) / sqrt(256) */

__device__ inline float bf2f(short s) {
    return __uint_as_float(((unsigned)(unsigned short)s) << 16);
}
__device__ inline short f2bf(float f) {
    unsigned u = __float_as_uint(f);
    return (short)((u + 0x7fffu + ((u >> 16) & 1u)) >> 16);
}
__device__ inline int cvtpk_bf16(float lo, float hi) {
    int d;
    asm("v_cvt_pk_bf16_f32 %0, %1, %2" : "=v"(d) : "v"(lo), "v"(hi));
    return d;
}
__device__ inline void gl_lds16(const void* g, void* l) {
    __builtin_amdgcn_global_load_lds(
        (const __attribute__((address_space(1))) unsigned int*)g,
        (__attribute__((address_space(3))) unsigned int*)l, 16, 0, 0);
}

// ---------------------------------------------------------------------------
// wprep2: sniff fused + W -> bf16 conversion (96 blocks).
// ---------------------------------------------------------------------------
__global__ __launch_bounds__(256) void wprep2(
    const void* __restrict__ Wq, const void* __restrict__ Wk,
    const void* __restrict__ Wv, const unsigned* __restrict__ x,
    int* __restrict__ flag, short* __restrict__ Wb)
{
    __shared__ int cs;
    if (threadIdx.x == 0) cs = 0;
    __syncthreads();
    int local = 0;
    for (int i = threadIdx.x; i < 1024; i += 256) {
        unsigned e = (x[i] >> 7) & 0xffu;
        if (e >= 100u && e <= 140u) local++;
    }
    atomicAdd(&cs, local);
    __syncthreads();
    const int isbf = (cs >= 512) ? 1 : 0;

    if (blockIdx.x == 0 && threadIdx.x == 0) flag[0] = isbf;

    const int base = (blockIdx.x * 256 + threadIdx.x) * 8;   // [0, 196608)
    const int wsel = base >> 16, off = base & 65535;
    const void* W = (wsel == 0) ? Wq : (wsel == 1) ? Wk : Wv;
    short8 v;
    if (isbf) {
        v = *(const short8*)((const short*)W + off);
    } else {
        const float* f = (const float*)W + off;
        float4 a = *(const float4*)f;
        float4 c4 = *(const float4*)(f + 4);
        v[0]=f2bf(a.x);  v[1]=f2bf(a.y);  v[2]=f2bf(a.z);  v[3]=f2bf(a.w);
        v[4]=f2bf(c4.x); v[5]=f2bf(c4.y); v[6]=f2bf(c4.z); v[7]=f2bf(c4.w);
    }
    *(short8*)(Wb + base) = v;
}

// ---------------------------------------------------------------------------
// qkv8b: R4-proven structure + dual MFMA accumulator chains (halves exposed
// MFMA dependency latency).  One block = 64 tokens x ONE of {Q,K,V}.
// Grid 768, 4 blocks/CU.  W register-double-buffered.
// ---------------------------------------------------------------------------
template <bool PIN>
__global__ __launch_bounds__(256, 4) void qkv8b(
    const void* __restrict__ xv, const short* __restrict__ Wb,
    const void* __restrict__ bq, const void* __restrict__ bk,
    const void* __restrict__ bv,
    const int* __restrict__ flag, int b0,
    short* __restrict__ qbase, short* __restrict__ kbase,
    short* __restrict__ vtbase)
{
    int nt, bl, wsel;
    if (PIN) {
        const int bid = blockIdx.x;          // 768
        wsel = bid >> 8;                      // 0..2
        const int rem = bid & 255;
        bl = rem & 3; nt = rem >> 2;
    } else { nt = blockIdx.x; wsel = blockIdx.y; bl = blockIdx.z; }
    const int b = b0 + bl;
    const int n0 = nt * 64;
    const int tid = threadIdx.x;
    const int w = tid >> 6, lane = tid & 63, l15 = lane & 15, qd = lane >> 4;
    const int isbf = flag[0];

    __shared__ short obuf[64 * 264];          // output staging only

    // ---- A-frags straight from global, coalesced: lane l15 = token ----
    short8 af[8];
    {
        const int n = n0 + 16 * w + l15;
        if (isbf) {
            const short* xs = (const short*)xv + (size_t)b * (CDIM * NTOK) + n;
            #pragma unroll
            for (int s = 0; s < 8; ++s) {
                short8 v;
                #pragma unroll
                for (int e = 0; e < 8; ++e)
                    v[e] = xs[(s * 32 + qd * 8 + e) * NTOK];
                af[s] = v;
            }
        } else {
            const float* xf = (const float*)xv + (size_t)b * (CDIM * NTOK) + n;
            #pragma unroll
            for (int s = 0; s < 8; ++s) {
                short8 v;
                #pragma unroll
                for (int e = 0; e < 8; ++e)
                    v[e] = f2bf(xf[(s * 32 + qd * 8 + e) * NTOK]);
                af[s] = v;
            }
        }
    }

    const short* W = Wb + wsel * 65536;
    const void* bp = (wsel == 0) ? bq : (wsel == 1) ? bk : bv;

    // ---- MFMA: 16 d-groups x 8 k-steps, W reg-double-buffered ----
    short8 wv[8], wn[8];
    {
        const short* wr = W + l15 * 256 + qd * 8;
        #pragma unroll
        for (int s = 0; s < 8; ++s) wv[s] = *(const short8*)(wr + s * 32);
    }
    #pragma unroll 1
    for (int dg = 0; dg < 16; ++dg) {
        const int d = dg * 16 + l15;
        if (dg + 1 < 16) {
            const short* wr = W + (dg * 16 + 16 + l15) * 256 + qd * 8;
            #pragma unroll
            for (int s = 0; s < 8; ++s) wn[s] = *(const short8*)(wr + s * 32);
        }
        // two independent accumulation chains
        float4_t ae = {0.f, 0.f, 0.f, 0.f};
        float4_t ao = {0.f, 0.f, 0.f, 0.f};
        #pragma unroll
        for (int s = 0; s < 4; ++s) {
            ae = __builtin_amdgcn_mfma_f32_16x16x32_bf16(af[2*s],   wv[2*s],   ae, 0, 0, 0);
            ao = __builtin_amdgcn_mfma_f32_16x16x32_bf16(af[2*s+1], wv[2*s+1], ao, 0, 0, 0);
        }
        const float bias = isbf ? bf2f(((const short*)bp)[d])
                                : ((const float*)bp)[d];
        if (wsel < 2) {
            #pragma unroll
            for (int r = 0; r < 4; ++r)
                obuf[(16 * w + 4 * qd + r) * 264 + d] = f2bf(ae[r] + ao[r] + bias);
        } else {
            #pragma unroll
            for (int r = 0; r < 4; ++r)
                obuf[d * 66 + (16 * w + 4 * qd + r)] = f2bf(ae[r] + ao[r] + bias);
        }
        #pragma unroll
        for (int s = 0; s < 8; ++s) wv[s] = wn[s];
    }
    __syncthreads();

    if (wsel == 0) {
        short* qdst = qbase + (size_t)bl * BPB;
        const int rl = tid >> 2;
        #pragma unroll
        for (int u = 0; u < 8; ++u) {
            const int cc = (tid & 3) + 4 * u;
            short8 vv = *(const short8*)&obuf[rl * 264 + cc * 8];
            *(short8*)(qdst + (size_t)(n0 + rl) * 256 + cc * 8) = vv;
        }
    } else if (wsel == 1) {
        short* kdst = kbase + (size_t)bl * BPB;
        const int rl = tid >> 2;
        const int tile = (n0 + rl) >> 5, rit = rl & 31;
        #pragma unroll
        for (int u = 0; u < 8; ++u) {
            const int ccp = (tid & 3) + 4 * u;          // stored position
            const int cc  = ccp ^ rit;                   // data chunk
            short8 vv = *(const short8*)&obuf[rl * 264 + cc * 8];
            *(short8*)(kdst + (size_t)tile * 8192 + rit * 256 + ccp * 8) = vv;
        }
    } else {
        short* vtdst = vtbase + (size_t)bl * BPB;
        const int d = tid;
        #pragma unroll
        for (int u = 0; u < 8; ++u) {
            short8 vv = *(const short8*)&obuf[d * 66 + u * 8];
            const int tile = (n0 >> 5) + (u >> 2), ck = u & 3;
            const int pos = ((d & 1) * 4 + ck) ^ ((d >> 1) & 7);
            *(short8*)(vtdst + (size_t)tile * 8192 + (d >> 1) * 64 + pos * 8) = vv;
        }
    }
}

// ---------------------------------------------------------------------------
// flash13 (R6-proven, 94 us): QBLK=128, 4 dedup waves, KVBLK=32, split4.
// One nearly-free barrier per iter.
// ---------------------------------------------------------------------------
__global__ __launch_bounds__(256, 2) void flash13(
    const short* __restrict__ qb, const short* __restrict__ kb,
    const short* __restrict__ vtb,
    float* __restrict__ pO, float* __restrict__ pl)
{
    const int bid = blockIdx.x;               // 512
    const int bl = bid & 3, half = (bid >> 2) & 3, qt = bid >> 4;
    const int q0 = qt * 128;
    const int tid = threadIdx.x;
    const int w = tid >> 6, lane = tid & 63, l31 = lane & 31, h = lane >> 5;

    __shared__ __align__(16) char smem[65536];
    short* kbufA = (short*)smem;               // 2 x 16 KB
    short* vbufA = (short*)(smem + 32768);     // 2 x 16 KB

    const short* Q  = qb  + (size_t)bl * BPB;
    const char*  Kc = (const char*)(kb  + (size_t)bl * BPB);
    const char*  Vc = (const char*)(vtb + (size_t)bl * BPB);

    short8 qf[16];
    {
        const short* qrow = Q + (size_t)(q0 + 32 * w + l31) * 256 + h * 8;
        #pragma unroll
        for (int s = 0; s < 16; ++s)
            qf[s] = *(const short8*)(qrow + s * 16);
    }

    float16_t oacc[8];
    #pragma unroll
    for (int dt = 0; dt < 8; ++dt)
        #pragma unroll
        for (int r = 0; r < 16; ++r) oacc[dt][r] = 0.f;
    float ll0 = 0.f, ll1 = 0.f, ll2 = 0.f, ll3 = 0.f;

    const int KT0 = half * 32, KT1 = KT0 + 32;

    {
        const char* ks = Kc + ((size_t)KT0 << 14);
        const char* vs = Vc + ((size_t)KT0 << 14);
        char* kd = smem + tid * 16;
        char* vd = smem + 32768 + tid * 16;
        #pragma unroll
        for (int u = 0; u < 4; ++u) {
            gl_lds16(ks + u * 4096 + tid * 16, kd + u * 4096);
            gl_lds16(vs + u * 4096 + tid * 16, vd + u * 4096);
        }
    }

    float16_t se, so;
    #pragma unroll
    for (int r = 0; r < 16; ++r) { se[r] = 0.f; so[r] = 0.f; }
    short8 pa0, pa1;

    #pragma unroll 1
    for (int kt = KT0; kt < KT1; ++kt) {
        // ================= phase A =================
        if (kt > KT0) {
            #pragma unroll
            for (int r = 0; r < 16; ++r) se[r] = exp2f((se[r] + so[r]) * C1);
            #pragma unroll
            for (int g = 0; g < 4; ++g) {
                ll0 += se[4 * g + 0]; ll1 += se[4 * g + 1];
                ll2 += se[4 * g + 2]; ll3 += se[4 * g + 3];
            }
            {
                int x0 = cvtpk_bf16(se[0], se[1]);
                int y0 = cvtpk_bf16(se[4], se[5]);
                int z0 = cvtpk_bf16(se[2], se[3]);
                int u0 = cvtpk_bf16(se[6], se[7]);
                int2_t r1 = __builtin_amdgcn_permlane32_swap(x0, y0, false, false);
                int2_t r2 = __builtin_amdgcn_permlane32_swap(z0, u0, false, false);
                union { int i[4]; short8 s8; } uu;
                uu.i[0] = r1[0]; uu.i[1] = r2[0]; uu.i[2] = r1[1]; uu.i[3] = r2[1];
                pa0 = uu.s8;
                int x1 = cvtpk_bf16(se[8],  se[9]);
                int y1 = cvtpk_bf16(se[12], se[13]);
                int z1 = cvtpk_bf16(se[10], se[11]);
                int u1 = cvtpk_bf16(se[14], se[15]);
                int2_t r3 = __builtin_amdgcn_permlane32_swap(x1, y1, false, false);
                int2_t r4 = __builtin_amdgcn_permlane32_swap(z1, u1, false, false);
                union { int i[4]; short8 s8; } vv;
                vv.i[0] = r3[0]; vv.i[1] = r4[0]; vv.i[2] = r3[1]; vv.i[3] = r4[1];
                pa1 = vv.s8;
            }
            {
                const short* vprev = vbufA + ((kt + 1) & 1) * 8192;  // (kt-1)&1
                #pragma unroll
                for (int dt = 0; dt < 8; ++dt) {
                    const int d = 32 * dt + l31, d2 = d >> 1;
                    {
                        const int pos = (((d & 1) * 4 + h) ^ (d2 & 7));
                        short8 vf = *(const short8*)&vprev[d2 * 64 + pos * 8];
                        oacc[dt] = __builtin_amdgcn_mfma_f32_32x32x16_bf16(pa0, vf, oacc[dt], 0, 0, 0);
                    }
                    {
                        const int pos = (((d & 1) * 4 + 2 + h) ^ (d2 & 7));
                        short8 vf = *(const short8*)&vprev[d2 * 64 + pos * 8];
                        oacc[dt] = __builtin_amdgcn_mfma_f32_32x32x16_bf16(pa1, vf, oacc[dt], 0, 0, 0);
                    }
                }
            }
        }

        asm volatile("s_waitcnt vmcnt(0) lgkmcnt(0)" ::: "memory");
        __builtin_amdgcn_sched_barrier(0);
        __builtin_amdgcn_s_barrier();
        __builtin_amdgcn_sched_barrier(0);

        // ================= phase B =================
        if (kt + 1 < KT1) {
            const int alt = (kt + 1) & 1;
            const char* ks = Kc + ((size_t)(kt + 1) << 14);
            const char* vs = Vc + ((size_t)(kt + 1) << 14);
            char* kd = smem + alt * 16384 + tid * 16;
            char* vd = smem + 32768 + alt * 16384 + tid * 16;
            #pragma unroll
            for (int u = 0; u < 4; ++u) {
                gl_lds16(ks + u * 4096 + tid * 16, kd + u * 4096);
                gl_lds16(vs + u * 4096 + tid * 16, vd + u * 4096);
            }
        }

        {
            const short* kcur = kbufA + (kt & 1) * 8192;
            #pragma unroll
            for (int r = 0; r < 16; ++r) { se[r] = 0.f; so[r] = 0.f; }
            #pragma unroll
            for (int j = 0; j < 8; ++j) {
                short8 ka = *(const short8*)
                    &kcur[l31 * 256 + (((4 * j + h) ^ l31) * 8)];
                se = __builtin_amdgcn_mfma_f32_32x32x16_bf16(ka, qf[2 * j], se, 0, 0, 0);
                short8 kb2 = *(const short8*)
                    &kcur[l31 * 256 + (((4 * j + 2 + h) ^ l31) * 8)];
                so = __builtin_amdgcn_mfma_f32_32x32x16_bf16(kb2, qf[2 * j + 1], so, 0, 0, 0);
            }
        }
    }

    // ---- drain ----
    {
        #pragma unroll
        for (int r = 0; r < 16; ++r) se[r] = exp2f((se[r] + so[r]) * C1);
        #pragma unroll
        for (int g = 0; g < 4; ++g) {
            ll0 += se[4 * g + 0]; ll1 += se[4 * g + 1];
            ll2 += se[4 * g + 2]; ll3 += se[4 * g + 3];
        }
        int x0 = cvtpk_bf16(se[0], se[1]);
        int y0 = cvtpk_bf16(se[4], se[5]);
        int z0 = cvtpk_bf16(se[2], se[3]);
        int u0 = cvtpk_bf16(se[6], se[7]);
        int2_t r1 = __builtin_amdgcn_permlane32_swap(x0, y0, false, false);
        int2_t r2 = __builtin_amdgcn_permlane32_swap(z0, u0, false, false);
        union { int i[4]; short8 s8; } uu;
        uu.i[0] = r1[0]; uu.i[1] = r2[0]; uu.i[2] = r1[1]; uu.i[3] = r2[1];
        pa0 = uu.s8;
        int x1 = cvtpk_bf16(se[8],  se[9]);
        int y1 = cvtpk_bf16(se[12], se[13]);
        int z1 = cvtpk_bf16(se[10], se[11]);
        int u1 = cvtpk_bf16(se[14], se[15]);
        int2_t r3 = __builtin_amdgcn_permlane32_swap(x1, y1, false, false);
        int2_t r4 = __builtin_amdgcn_permlane32_swap(z1, u1, false, false);
        union { int i[4]; short8 s8; } vv;
        vv.i[0] = r3[0]; vv.i[1] = r4[0]; vv.i[2] = r3[1]; vv.i[3] = r4[1];
        pa1 = vv.s8;

        const short* vlast = vbufA + 8192;     // (KT1-1)&1 == 1 always
        #pragma unroll
        for (int dt = 0; dt < 8; ++dt) {
            const int d = 32 * dt + l31, d2 = d >> 1;
            {
                const int pos = (((d & 1) * 4 + h) ^ (d2 & 7));
                short8 vf = *(const short8*)&vlast[d2 * 64 + pos * 8];
                oacc[dt] = __builtin_amdgcn_mfma_f32_32x32x16_bf16(pa0, vf, oacc[dt], 0, 0, 0);
            }
            {
                const int pos = (((d & 1) * 4 + 2 + h) ^ (d2 & 7));
                short8 vf = *(const short8*)&vlast[d2 * 64 + pos * 8];
                oacc[dt] = __builtin_amdgcn_mfma_f32_32x32x16_bf16(pa1, vf, oacc[dt], 0, 0, 0);
            }
        }
    }

    // ---- epilogue: direct partial stores ----
    const size_t idx = (size_t)(bl * 32 + qt) * 4 + half;
    {
        float v2 = (ll0 + ll1) + (ll2 + ll3);
        v2 += __shfl_xor(v2, 32, 64);
        if (h == 0) pl[idx * 128 + 32 * w + l31] = v2;
    }
    float* po = pO + idx * 32768;
    #pragma unroll
    for (int dt = 0; dt < 8; ++dt) {
        #pragma unroll
        for (int r = 0; r < 16; ++r) {
            const int qrow = 32 * w + (r & 3) + 8 * (r >> 2) + 4 * h;
            po[qrow * 256 + 32 * dt + l31] = oacc[dt][r];
        }
    }
}

// ---------------------------------------------------------------------------
// combine4 (R5-proven, coalesced): one wave = one output row.  Grid 512,
// 8 rows/wave -> 2 blocks/CU.
// ---------------------------------------------------------------------------
__global__ __launch_bounds__(256) void combine4(
    const float* __restrict__ pO, const float* __restrict__ pl,
    const int* __restrict__ flag, void* __restrict__ outv)
{
    const int tid = threadIdx.x, w = tid >> 6, lane = tid & 63;
    const int isbf = flag[0];
    #pragma unroll 1
    for (int st = 0; st < 8; ++st) {
        const int row = blockIdx.x * 32 + st * 4 + w;     // [0, 16384)
        const int bl = row >> 12, n = row & 4095;
        const int qt = n >> 7, prow = n & 127;
        const size_t bidx = (size_t)(bl * 32 + qt) * 4;
        const float* P0 = pO + bidx * 32768 + prow * 256 + lane * 4;
        float4 a = *(const float4*)P0;
        float4 b = *(const float4*)(P0 + 32768);
        float4 c = *(const float4*)(P0 + 65536);
        float4 d = *(const float4*)(P0 + 98304);
        const float inv = 1.0f /
            (pl[(bidx + 0) * 128 + prow] + pl[(bidx + 1) * 128 + prow] +
             pl[(bidx + 2) * 128 + prow] + pl[(bidx + 3) * 128 + prow]);
        float4 r;
        r.x = (a.x + b.x + c.x + d.x) * inv;
        r.y = (a.y + b.y + c.y + d.y) * inv;
        r.z = (a.z + b.z + c.z + d.z) * inv;
        r.w = (a.w + b.w + c.w + d.w) * inv;
        const size_t o = (size_t)row * 256 + lane * 4;
        if (isbf) {
            short4_t pk;
            pk[0] = f2bf(r.x); pk[1] = f2bf(r.y);
            pk[2] = f2bf(r.z); pk[3] = f2bf(r.w);
            *(short4_t*)((short*)outv + o) = pk;
        } else {
            *(float4*)((float*)outv + o) = r;
        }
    }
}

// ---------------------------------------------------------------------------
// flash12 (small-ws fallback): QBLK=64, KVBLK=32, no split, direct output.
// ---------------------------------------------------------------------------
template <bool PIN>
__global__ __launch_bounds__(256, 2) void flash12(
    int b0, const short* __restrict__ qb, const short* __restrict__ kb,
    const short* __restrict__ vtb, const int* __restrict__ flag,
    void* __restrict__ outv)
{
    int qt, bl;
    if (PIN) { bl = blockIdx.x & 3; qt = blockIdx.x >> 2; }
    else     { qt = blockIdx.x; bl = blockIdx.z; }

    const int b = b0 + bl;
    const int q0 = qt * 64;
    const int tid = threadIdx.x;
    const int w = tid >> 6, lane = tid & 63, l31 = lane & 31, h = lane >> 5;
    const int wi = w & 1, wh = w >> 1;

    __shared__ __align__(16) char smem[67584];
    short* kbufA = (short*)smem;
    short* vbufA = (short*)(smem + 32768);
    float* lbuf  = (float*)(smem + 66560);

    const short* Q  = qb  + (size_t)bl * BPB;
    const char*  Kc = (const char*)(kb  + (size_t)bl * BPB);
    const char*  Vc = (const char*)(vtb + (size_t)bl * BPB);

    short8 qf[16];
    {
        const short* qrow = Q + (size_t)(q0 + 32 * wh + l31) * 256 + h * 8;
        #pragma unroll
        for (int s = 0; s < 16; ++s)
            qf[s] = *(const short8*)(qrow + s * 16);
    }

    float16_t oacc[4];
    #pragma unroll
    for (int dt = 0; dt < 4; ++dt)
        #pragma unroll
        for (int r = 0; r < 16; ++r) oacc[dt][r] = 0.f;
    float ll0 = 0.f, ll1 = 0.f, ll2 = 0.f, ll3 = 0.f;

    {
        const char* ks = Kc;
        const char* vs = Vc;
        char* kd = smem + tid * 16;
        char* vd = smem + 32768 + tid * 16;
        #pragma unroll
        for (int u = 0; u < 4; ++u) {
            gl_lds16(ks + u * 4096 + tid * 16, kd + u * 4096);
            gl_lds16(vs + u * 4096 + tid * 16, vd + u * 4096);
        }
    }
    __syncthreads();

    short8 pa0 = {0,0,0,0,0,0,0,0}, pa1 = {0,0,0,0,0,0,0,0};

    #pragma unroll 1
    for (int kt = 0; kt < 128; ++kt) {
        short* kcur  = kbufA + (kt & 1) * 8192;
        short* vprev = vbufA + ((kt + 1) & 1) * 8192;

        if (kt + 1 < 128) {
            const char* ks = Kc + ((size_t)(kt + 1) << 14);
            char* kd = smem + (((kt + 1) & 1) << 14) + tid * 16;
            #pragma unroll
            for (int u = 0; u < 4; ++u)
                gl_lds16(ks + u * 4096 + tid * 16, kd + u * 4096);
        }

        float16_t se, so;
        #pragma unroll
        for (int r = 0; r < 16; ++r) { se[r] = 0.f; so[r] = 0.f; }
        #pragma unroll
        for (int j = 0; j < 8; ++j) {
            short8 ka = *(const short8*)
                &kcur[l31 * 256 + (((4 * j + h) ^ l31) * 8)];
            se = __builtin_amdgcn_mfma_f32_32x32x16_bf16(ka, qf[2 * j], se, 0, 0, 0);
            short8 kb2 = *(const short8*)
                &kcur[l31 * 256 + (((4 * j + 2 + h) ^ l31) * 8)];
            so = __builtin_amdgcn_mfma_f32_32x32x16_bf16(kb2, qf[2 * j + 1], so, 0, 0, 0);
        }

        if (kt > 0) {
            #pragma unroll
            for (int dt = 0; dt < 4; ++dt) {
                const int d = 128 * wi + 32 * dt + l31, d2 = d >> 1;
                {
                    const int pos = (((d & 1) * 4 + h) ^ (d2 & 7));
                    short8 vf = *(const short8*)&vprev[d2 * 64 + pos * 8];
                    oacc[dt] = __builtin_amdgcn_mfma_f32_32x32x16_bf16(pa0, vf, oacc[dt], 0, 0, 0);
                }
                {
                    const int pos = (((d & 1) * 4 + 2 + h) ^ (d2 & 7));
                    short8 vf = *(const short8*)&vprev[d2 * 64 + pos * 8];
                    oacc[dt] = __builtin_amdgcn_mfma_f32_32x32x16_bf16(pa1, vf, oacc[dt], 0, 0, 0);
                }
            }
        }

        asm volatile("s_waitcnt lgkmcnt(0)" ::: "memory");
        __builtin_amdgcn_sched_barrier(0);
        __builtin_amdgcn_s_barrier();
        __builtin_amdgcn_sched_barrier(0);

        if (kt + 1 < 128) {
            const char* vs = Vc + ((size_t)(kt + 1) << 14);
            char* vd = smem + 32768 + (((kt + 1) & 1) << 14) + tid * 16;
            #pragma unroll
            for (int u = 0; u < 4; ++u)
                gl_lds16(vs + u * 4096 + tid * 16, vd + u * 4096);
        }

        float pf[16];
        #pragma unroll
        for (int r = 0; r < 16; ++r) pf[r] = exp2f((se[r] + so[r]) * C1);
        #pragma unroll
        for (int g = 0; g < 4; ++g) {
            ll0 += pf[4 * g + 0]; ll1 += pf[4 * g + 1];
            ll2 += pf[4 * g + 2]; ll3 += pf[4 * g + 3];
        }
        {
            int x0 = cvtpk_bf16(pf[0], pf[1]);
            int y0 = cvtpk_bf16(pf[4], pf[5]);
            int z0 = cvtpk_bf16(pf[2], pf[3]);
            int u0 = cvtpk_bf16(pf[6], pf[7]);
            int2_t r1 = __builtin_amdgcn_permlane32_swap(x0, y0, false, false);
            int2_t r2 = __builtin_amdgcn_permlane32_swap(z0, u0, false, false);
            union { int i[4]; short8 s8; } uu;
            uu.i[0] = r1[0]; uu.i[1] = r2[0]; uu.i[2] = r1[1]; uu.i[3] = r2[1];
            pa0 = uu.s8;
            int x1 = cvtpk_bf16(pf[8],  pf[9]);
            int y1 = cvtpk_bf16(pf[12], pf[13]);
            int z1 = cvtpk_bf16(pf[10], pf[11]);
            int u1 = cvtpk_bf16(pf[14], pf[15]);
            int2_t r3 = __builtin_amdgcn_permlane32_swap(x1, y1, false, false);
            int2_t r4 = __builtin_amdgcn_permlane32_swap(z1, u1, false, false);
            union { int i[4]; short8 s8; } vv;
            vv.i[0] = r3[0]; vv.i[1] = r4[0]; vv.i[2] = r3[1]; vv.i[3] = r4[1];
            pa1 = vv.s8;
        }

        __syncthreads();
    }

    {
        short* vlast = vbufA + 8192;
        #pragma unroll
        for (int dt = 0; dt < 4; ++dt) {
            const int d = 128 * wi + 32 * dt + l31, d2 = d >> 1;
            {
                const int pos = (((d & 1) * 4 + h) ^ (d2 & 7));
                short8 vf = *(const short8*)&vlast[d2 * 64 + pos * 8];
                oacc[dt] = __builtin_amdgcn_mfma_f32_32x32x16_bf16(pa0, vf, oacc[dt], 0, 0, 0);
            }
            {
                const int pos = (((d & 1) * 4 + 2 + h) ^ (d2 & 7));
                short8 vf = *(const short8*)&vlast[d2 * 64 + pos * 8];
                oacc[dt] = __builtin_amdgcn_mfma_f32_32x32x16_bf16(pa1, vf, oacc[dt], 0, 0, 0);
            }
        }
    }

    {
        float v2 = (ll0 + ll1) + (ll2 + ll3);
        v2 += __shfl_xor(v2, 32, 64);
        if (h == 0 && wi == 0) lbuf[32 * wh + l31] = v2;
    }

    __syncthreads();
    float* obuf = (float*)smem;
    #pragma unroll
    for (int dt = 0; dt < 4; ++dt) {
        const int dim = 128 * wi + 32 * dt + l31;
        #pragma unroll
        for (int r = 0; r < 16; ++r) {
            const int qrow = 32 * wh + (r & 3) + 8 * (r >> 2) + 4 * h;
            obuf[qrow * 260 + dim] = oacc[dt][r];
        }
    }
    __syncthreads();
    {
        const int row = tid >> 2, q4 = (tid & 3) * 64;
        const float inv = 1.0f / lbuf[row];
        const float* src = obuf + row * 260 + q4;
        const size_t o = (size_t)(b * NTOK + q0 + row) * 256 + q4;
        if (flag[0]) {
            short* op = (short*)outv;
            #pragma unroll
            for (int g = 0; g < 4; ++g) {
                float4 a  = *(const float4*)(src + g * 8);
                float4 c4 = *(const float4*)(src + g * 8 + 4);
                short8 pk;
                pk[0]=f2bf(a.x*inv);  pk[1]=f2bf(a.y*inv);
                pk[2]=f2bf(a.z*inv);  pk[3]=f2bf(a.w*inv);
                pk[4]=f2bf(c4.x*inv); pk[5]=f2bf(c4.y*inv);
                pk[6]=f2bf(c4.z*inv); pk[7]=f2bf(c4.w*inv);
                *(short8*)(op + o + g * 8) = pk;
            }
        } else {
            float* op = (float*)outv;
            #pragma unroll
            for (int g = 0; g < 16; ++g) {
                float4 a = *(const float4*)(src + g * 4);
                a.x *= inv; a.y *= inv; a.z *= inv; a.w *= inv;
                *(float4*)(op + o + g * 4) = a;
            }
        }
    }
}

extern "C" void kernel_launch(void* const* d_in, const int* in_sizes, int n_in,
                              void* d_out, int out_size, void* d_ws, size_t ws_size,
                              hipStream_t stream)
{
    const size_t HDR = 1024;
    const size_t WBB = 393216;                     // 3 x 256 x 256 bf16
    const size_t TB  = (size_t)BPB * 2;            // 2 MB per batch per tensor
    const size_t OFF_K = HDR + WBB;
    const size_t need_prim = OFF_K + 12 * TB;                  // ~24.6 MB
    const size_t PO4 = 67108864;                                // split4 partials
    const size_t need_s4 = need_prim + PO4 + 262144;            // ~92 MB

    int*   flag = (int*)d_ws;
    short* Wb   = (short*)((char*)d_ws + HDR);

    wprep2<<<96, 256, 0, stream>>>(
        d_in[1], d_in[3], d_in[5], (const unsigned*)d_in[0], flag, Wb);

    if (ws_size >= need_prim) {
        short* kbase  = (short*)((char*)d_ws + OFF_K);
        short* vtbase = kbase  + 4 * (size_t)BPB;
        short* qbase  = vtbase + 4 * (size_t)BPB;
        qkv8b<true><<<dim3(768, 1, 1), 256, 0, stream>>>(
            d_in[0], Wb, d_in[2], d_in[4], d_in[6], flag, 0,
            qbase, kbase, vtbase);
        if (ws_size >= need_s4) {
            float* pO = (float*)((char*)d_ws + need_prim);
            float* pl = (float*)((char*)d_ws + need_prim + PO4);
            flash13<<<dim3(512, 1, 1), 256, 0, stream>>>(
                qbase, kbase, vtbase, pO, pl);
            combine4<<<dim3(512, 1, 1), 256, 0, stream>>>(pO, pl, flag, d_out);
        } else {
            flash12<true><<<dim3(256, 1, 1), 256, 0, stream>>>(
                0, qbase, kbase, vtbase, flag, d_out);
        }
        return;
    }

    // fallback: batch-chunked
    int nb = 4;
    while (nb > 1 && ws_size < OFF_K + (size_t)nb * 3 * TB) nb--;
    short* kbase  = (short*)((char*)d_ws + OFF_K);
    short* vtbase = kbase + (size_t)nb * BPB;
    short* qbase  = vtbase + (size_t)nb * BPB;

    for (int b0 = 0; b0 < 4; b0 += nb) {
        const int nbc = (4 - b0) < nb ? (4 - b0) : nb;
        qkv8b<false><<<dim3(64, 3, nbc), 256, 0, stream>>>(
            d_in[0], Wb, d_in[2], d_in[4], d_in[6], flag, b0,
            qbase, kbase, vtbase);
        flash12<false><<<dim3(64, 1, nbc), 256, 0, stream>>>(
            b0, qbase, kbase, vtbase, flag, d_out);
    }
}